// Round 5
// baseline (124.410 us; speedup 1.0000x reference)
//
#include <hip/hip_runtime.h>
#include <hip/hip_bf16.h>

// B=256, C_IN=6, L=512, C1=32, C2=D=64, NCLASS=10.
// Megakernel v14: single-kernel. prep_weights is ELIMINATED — each block
// folds w1/w2 (+BN) into LDS during P0 (frag-slot order [f][lane][8], same
// conflict-free contiguous read pattern as Kf/Vf), and gathers wq/wk/wv
// RAW from L2 in the conv phase: the sigma_h permutation maps each bf16x8
// fragment to two contiguous float4 runs of the raw matrix, so no prefold
// is needed (QSC now applied at the aQ pack: (a+bq)*QSC, identical math).
// Attention loop (v13) untouched. LDS 154368 B. ws unused.

#define NB 256
#define LL 512
#define CIN 6
#define NCLASS 10
#define SLAB 8192
#define QSC 0.18033688f   // 0.125 * log2(e): exp(s/8) == exp2(s*QSC)

typedef __bf16 bf16x8 __attribute__((ext_vector_type(8)));
typedef float f32x4 __attribute__((ext_vector_type(4)));
typedef unsigned short us4 __attribute__((ext_vector_type(4)));
typedef unsigned short us8 __attribute__((ext_vector_type(8)));
typedef unsigned int u32x4 __attribute__((ext_vector_type(4)));

static __device__ __forceinline__ unsigned short f2b(float f) {
    __bf16 h = (__bf16)f;                       // RNE f32->bf16
    return __builtin_bit_cast(unsigned short, h);
}

// Gather one A/B fragment from a RAW [64][64] f32 matrix under sigma_h:
// frag elem e <- row d, col ch = base + (e>>2)*16 + quad*4 + (e&3).
static __device__ __forceinline__ bf16x8 gather_w(const float* __restrict__ wrow,
                                                  int base, int quad) {
    f32x4 a = *(const f32x4*)(wrow + base + quad * 4);
    f32x4 b = *(const f32x4*)(wrow + base + 16 + quad * 4);
    bf16x8 r;
    #pragma unroll
    for (int e = 0; e < 4; e++) { r[e] = (__bf16)a[e]; r[4 + e] = (__bf16)b[e]; }
    return r;
}

// ---------------------------------------------------------------------------
// Megakernel v14. LDS map (byte offsets, all 16B-aligned):
//   [0,131072)        16 slabs x 8192: conv h1sl[34][40]@0 ; attn Kf@0, Vf@4096
//   [131072,139264)   xstage [512][8] u16 (dead after P1; epilogue redw/pooled)
//   [139264,151552)   w2f [12][64][8] u16  (f = kc*4+nt, frag-slot order)
//   [151552,153600)   w1f [2][64][8] u16
//   [153600,153728)   b1f f32[32]   [153728,153984) b2f f32[64]
//   [153984,154112)   inv1 f32[32]  [154112,154368) inv2 f32[64]
// ---------------------------------------------------------------------------
__global__ __launch_bounds__(512, 2) void fused_all(
    const float* __restrict__ x,
    const float* __restrict__ w1, const float* __restrict__ cb1,
    const float* __restrict__ g1, const float* __restrict__ be1,
    const float* __restrict__ m1, const float* __restrict__ v1,
    const float* __restrict__ w2, const float* __restrict__ cb2,
    const float* __restrict__ g2, const float* __restrict__ be2,
    const float* __restrict__ m2, const float* __restrict__ v2,
    const float* __restrict__ wq, const float* __restrict__ bq,
    const float* __restrict__ wk, const float* __restrict__ bk,
    const float* __restrict__ wv, const float* __restrict__ bv,
    const float* __restrict__ fcw, const float* __restrict__ fcb,
    float* __restrict__ outp)
{
    const int b = blockIdx.x;
    const int t = threadIdx.x;
    const int w = t >> 6, lane = t & 63, quad = lane >> 4, lc = lane & 15;

    __shared__ __align__(16) char smem[154368];
    unsigned short* xstage = (unsigned short*)(smem + 131072);     // [512][8]
    unsigned short* w2f = (unsigned short*)(smem + 139264);
    unsigned short* w1f = (unsigned short*)(smem + 151552);
    float* b1fl  = (float*)(smem + 153600);
    float* b2fl  = (float*)(smem + 153728);
    float* inv1l = (float*)(smem + 153984);
    float* inv2l = (float*)(smem + 154112);
    float* redw   = (float*)(smem + 131072) + w * 64;   // epilogue (xstage dead)
    float* pooled = (float*)(smem + 131072 + 4096);

    unsigned short* slab[2] = { (unsigned short*)(smem + (2 * w) * SLAB),
                                (unsigned short*)(smem + (2 * w + 1) * SLAB) };

    // ---- P0a: stage x[b] transposed to [pos][ch(8)] bf16 (b128 rows) -----
    {
        us8 pk;
        #pragma unroll
        for (int ci = 0; ci < 6; ci++)
            pk[ci] = f2b(x[((size_t)b * CIN + ci) * LL + t]);  // coalesced per ci
        pk[6] = 0; pk[7] = 0;
        *(us8*)&xstage[t * 8] = pk;
    }
    // ---- P0b: BN inv/bias tables -----------------------------------------
    if (t < 32) {
        float iv = g1[t] * rsqrtf(v1[t] + 1e-5f);
        inv1l[t] = iv;
        b1fl[t] = be1[t] + (cb1[t] - m1[t]) * iv;
    } else if (t < 96) {
        int c2 = t - 32;
        float iv = g2[c2] * rsqrtf(v2[c2] + 1e-5f);
        inv2l[c2] = iv;
        b2fl[c2] = be2[c2] + (cb2[c2] - m2[c2]) * iv;
    }
    __syncthreads();                                  // inv tables ready

    // ---- P0c: fold w1/w2 into frag-slot-order LDS ------------------------
    // w2f entry idx = f*512 + lane2*8 + e, f = kc*4+nt:
    //   value = w2[c2=nt*16+lc2][ci=q2*8+e][dl=kc] * inv2[c2]
    for (int idx = t; idx < 6144; idx += 512) {
        int e = idx & 7, lane2 = (idx >> 3) & 63, f = idx >> 9;
        int nt = f & 3, kc = f >> 2;
        int q2 = lane2 >> 4, lc2 = lane2 & 15;
        int c2 = nt * 16 + lc2, ci = q2 * 8 + e;
        w2f[idx] = f2b(w2[c2 * 96 + ci * 3 + kc] * inv2l[c2]);
    }
    for (int idx = t; idx < 1024; idx += 512) {
        int e = idx & 7, lane2 = (idx >> 3) & 63, nt = idx >> 9;
        int q2 = lane2 >> 4, lc2 = lane2 & 15;
        int c = nt * 16 + lc2;
        float val = (q2 < 3 && e < 6) ? w1[c * 18 + e * 3 + q2] * inv1l[c] : 0.f;
        w1f[idx] = f2b(val);
    }
    __syncthreads();                                  // weights + xstage ready

    // ---- P1: conv1 swapped: h1 = mfma(W1, X), both groups ----------------
    {
        bf16x8 bW1[2];
        #pragma unroll
        for (int nt = 0; nt < 2; nt++)
            bW1[nt] = *(const bf16x8*)&w1f[nt * 512 + lane * 8];
        f32x4 b1q[2];
        #pragma unroll
        for (int nt = 0; nt < 2; nt++)
            b1q[nt] = *(const f32x4*)&b1fl[nt * 16 + quad * 4];
        #pragma unroll
        for (int sg = 0; sg < 2; sg++) {
            const int g = 2 * w + sg;
            unsigned short* h1sl = slab[sg];
            #pragma unroll
            for (int mt = 0; mt < 3; mt++) {
                int j = mt * 16 + lc;                 // 0..47, keep <34
                int P = g * 32 - 1 + j;               // output position (halo +-1)
                int src = P + quad - 1;               // x position for dl=quad
                bool okx = (src >= 0) && (src < LL);  // quad==3 -> weight is zero
                int srcc = src < 0 ? 0 : (src > 511 ? 511 : src);
                u32x4 xv = *(const u32x4*)&xstage[srcc * 8];
                if (!okx) { xv[0] = 0u; xv[1] = 0u; xv[2] = 0u; xv[3] = 0u; }
                bf16x8 aX = __builtin_bit_cast(bf16x8, xv);
                bool pv = (P >= 0) && (P < LL);
                #pragma unroll
                for (int nt = 0; nt < 2; nt++) {
                    f32x4 z = {0.f, 0.f, 0.f, 0.f};
                    f32x4 h = __builtin_amdgcn_mfma_f32_16x16x32_bf16(bW1[nt], aX, z, 0, 0, 0);
                    us4 pk;
                    #pragma unroll
                    for (int r = 0; r < 4; r++) {
                        float y = h[r] + b1q[nt][r];
                        y = (pv && y > 0.f) ? y : 0.f;
                        pk[r] = f2b(y);
                    }
                    if (j < 34)
                        *(us4*)&h1sl[j * 40 + nt * 16 + quad * 4] = pk;
                }
            }
        }
    }

    // ---- P2: conv2 as GEMM; weights from LDS, sg x rt chains -------------
    bf16x8 bX[2][2][3];                   // [sg][rt][kc]
    #pragma unroll
    for (int sg = 0; sg < 2; sg++)
        #pragma unroll
        for (int rt = 0; rt < 2; rt++)
            #pragma unroll
            for (int kc = 0; kc < 3; kc++)
                bX[sg][rt][kc] = *(const bf16x8*)&slab[sg][(rt * 16 + lc + kc) * 40 + quad * 8];

    f32x4 acc2[2][4][2];                  // [sg][nt][rt]
    #pragma unroll
    for (int nt = 0; nt < 4; nt++) {
        bf16x8 aW0 = *(const bf16x8*)&w2f[(0 * 4 + nt) * 512 + lane * 8];
        bf16x8 aW1 = *(const bf16x8*)&w2f[(1 * 4 + nt) * 512 + lane * 8];
        bf16x8 aW2 = *(const bf16x8*)&w2f[(2 * 4 + nt) * 512 + lane * 8];
        #pragma unroll
        for (int sg = 0; sg < 2; sg++)
            #pragma unroll
            for (int rt = 0; rt < 2; rt++) {
                f32x4 a = {0.f, 0.f, 0.f, 0.f};
                a = __builtin_amdgcn_mfma_f32_16x16x32_bf16(aW0, bX[sg][rt][0], a, 0, 0, 0);
                a = __builtin_amdgcn_mfma_f32_16x16x32_bf16(aW1, bX[sg][rt][1], a, 0, 0, 0);
                acc2[sg][nt][rt] = __builtin_amdgcn_mfma_f32_16x16x32_bf16(aW2, bX[sg][rt][2], a, 0, 0, 0);
            }
    }

    // ---- P3a: +b2f, relu -> aH in REGISTERS (sigma_h frag order) ---------
    bf16x8 aH[2][2][2];                   // [sg][rt][kc]
    #pragma unroll
    for (int nt2 = 0; nt2 < 4; nt2++) {
        f32x4 bb2 = *(const f32x4*)&b2fl[nt2 * 16 + quad * 4];
        #pragma unroll
        for (int sg = 0; sg < 2; sg++)
            #pragma unroll
            for (int rt = 0; rt < 2; rt++)
                #pragma unroll
                for (int reg = 0; reg < 4; reg++) {
                    float y = acc2[sg][nt2][rt][reg] + bb2[reg];
                    aH[sg][rt][nt2 >> 1][(nt2 & 1) * 4 + reg] = (__bf16)(y > 0.f ? y : 0.f);
                }
    }

    // ---- biases for q/k (hoisted) ----------------------------------------
    f32x4 bbq[4], bbk[4];
    #pragma unroll
    for (int nt = 0; nt < 4; nt++) {
        bbq[nt] = *(const f32x4*)&bq[nt * 16 + quad * 4];
        bbk[nt] = *(const f32x4*)&bk[nt * 16 + quad * 4];
    }

    // ---- P3b-q: q fully in registers (sigma_d frag order), raw-wq gather -
    bf16x8 aQ4[4][2];                     // [rt4 = sg*2+rt][kc]
    #pragma unroll
    for (int nt = 0; nt < 4; nt++) {
        const float* wqr = wq + (nt * 16 + lc) * 64;
        bf16x8 aW0 = gather_w(wqr, 0, quad);
        bf16x8 aW1 = gather_w(wqr, 32, quad);
        #pragma unroll
        for (int sg = 0; sg < 2; sg++)
            #pragma unroll
            for (int rt = 0; rt < 2; rt++) {
                f32x4 a = {0.f, 0.f, 0.f, 0.f};
                a = __builtin_amdgcn_mfma_f32_16x16x32_bf16(aW0, aH[sg][rt][0], a, 0, 0, 0);
                a = __builtin_amdgcn_mfma_f32_16x16x32_bf16(aW1, aH[sg][rt][1], a, 0, 0, 0);
                #pragma unroll
                for (int reg = 0; reg < 4; reg++)
                    aQ4[sg * 2 + rt][nt >> 1][(nt & 1) * 4 + reg] =
                        (__bf16)((a[reg] + bbq[nt][reg]) * QSC);
            }
    }

    // ---- P3b-k: k -> Kf as 4 x b128 (sigma_d order), raw-wk gather -------
    #pragma unroll
    for (int kc = 0; kc < 2; kc++) {
        f32x4 Ck[2][2][2];                // [j][sg][rt], nt = kc*2+j
        #pragma unroll
        for (int j = 0; j < 2; j++) {
            int nt = kc * 2 + j;
            const float* wkr = wk + (nt * 16 + lc) * 64;
            bf16x8 aW0 = gather_w(wkr, 0, quad);
            bf16x8 aW1 = gather_w(wkr, 32, quad);
            #pragma unroll
            for (int sg = 0; sg < 2; sg++)
                #pragma unroll
                for (int rt = 0; rt < 2; rt++) {
                    f32x4 a = {0.f, 0.f, 0.f, 0.f};
                    a = __builtin_amdgcn_mfma_f32_16x16x32_bf16(aW0, aH[sg][rt][0], a, 0, 0, 0);
                    Ck[j][sg][rt] = __builtin_amdgcn_mfma_f32_16x16x32_bf16(aW1, aH[sg][rt][1], a, 0, 0, 0);
                }
        }
        #pragma unroll
        for (int sg = 0; sg < 2; sg++)
            #pragma unroll
            for (int rt = 0; rt < 2; rt++) {
                us8 pk;
                #pragma unroll
                for (int e = 0; e < 8; e++) {
                    int j = e >> 2, reg = e & 3, nt = kc * 2 + j;
                    pk[e] = f2b(Ck[j][sg][rt][reg] + bbk[nt][reg]);
                }
                *(us8*)&slab[sg][((rt * 2 + kc) << 9) + lane * 8] = pk;   // Kf
            }
    }

    // ---- P3c: v -> Vf as 4 x b128 (key-permuted frag order), raw-wv ------
    #pragma unroll
    for (int nt = 0; nt < 4; nt++) {
        const float* wvr = wv + (nt * 16 + lc) * 64;
        bf16x8 bW0 = gather_w(wvr, 0, quad);
        bf16x8 bW1 = gather_w(wvr, 32, quad);
        const float bvv = bv[nt * 16 + lc];
        #pragma unroll
        for (int sg = 0; sg < 2; sg++) {
            f32x4 a0, a1;
            {
                f32x4 z = {0.f, 0.f, 0.f, 0.f};
                z = __builtin_amdgcn_mfma_f32_16x16x32_bf16(aH[sg][0][0], bW0, z, 0, 0, 0);
                a0 = __builtin_amdgcn_mfma_f32_16x16x32_bf16(aH[sg][0][1], bW1, z, 0, 0, 0);
            }
            {
                f32x4 z = {0.f, 0.f, 0.f, 0.f};
                z = __builtin_amdgcn_mfma_f32_16x16x32_bf16(aH[sg][1][0], bW0, z, 0, 0, 0);
                a1 = __builtin_amdgcn_mfma_f32_16x16x32_bf16(aH[sg][1][1], bW1, z, 0, 0, 0);
            }
            us8 pk;
            #pragma unroll
            for (int reg = 0; reg < 4; reg++) {
                pk[reg]     = f2b(a0[reg] + bvv);
                pk[4 + reg] = f2b(a1[reg] + bvv);
            }
            *(us8*)&slab[sg][2048 + nt * 512 + lane * 8] = pk;            // Vf
        }
    }

    __syncthreads();          // all waves' Kf/Vf ready — only pre-attn barrier

    // ---- attention: 16 chunks, 64 q/wave, in-reg softmax, pipelined ------
    f32x4 outacc[4][4];
    #pragma unroll
    for (int rt = 0; rt < 4; rt++)
        #pragma unroll
        for (int dt = 0; dt < 4; dt++) outacc[rt][dt] = (f32x4){0.f, 0.f, 0.f, 0.f};
    f32x4 accDen[4];
    #pragma unroll
    for (int rt = 0; rt < 4; rt++) accDen[rt] = (f32x4){0.f, 0.f, 0.f, 0.f};
    bf16x8 bOne;
    #pragma unroll
    for (int e = 0; e < 8; e++) bOne[e] = (__bf16)1.0f;

    bf16x8 bK2[2][2];
    {
        const unsigned short* sK = (const unsigned short*)smem;   // chunk 0
        #pragma unroll
        for (int nt = 0; nt < 2; nt++)
            #pragma unroll
            for (int kc = 0; kc < 2; kc++)
                bK2[nt][kc] = *(const bf16x8*)&sK[((nt * 2 + kc) << 9) + lane * 8];
    }
    f32x4 sv[2][4];                               // [nt][rt4]
    #pragma unroll
    for (int nt = 0; nt < 2; nt++)
        #pragma unroll
        for (int rt = 0; rt < 4; rt++) {
            f32x4 z = {0.f, 0.f, 0.f, 0.f};
            z = __builtin_amdgcn_mfma_f32_16x16x32_bf16(bK2[nt][0], aQ4[rt][0], z, 0, 0, 0);
            sv[nt][rt] = __builtin_amdgcn_mfma_f32_16x16x32_bf16(bK2[nt][1], aQ4[rt][1], z, 0, 0, 0);
        }

    for (int cc = 0; cc < 16; cc++) {
        const unsigned short* sV = (const unsigned short*)(smem + cc * SLAB + 4096);
        bf16x8 bV[4];
        #pragma unroll
        for (int dt = 0; dt < 4; dt++)
            bV[dt] = *(const bf16x8*)&sV[dt * 512 + lane * 8];
        if (cc < 15) {                            // load next chunk's K frags
            const unsigned short* sKn = (const unsigned short*)(smem + (cc + 1) * SLAB);
            #pragma unroll
            for (int nt = 0; nt < 2; nt++)
                #pragma unroll
                for (int kc = 0; kc < 2; kc++)
                    bK2[nt][kc] = *(const bf16x8*)&sKn[((nt * 2 + kc) << 9) + lane * 8];
        }
        bf16x8 aP[4];
        #pragma unroll
        for (int rt = 0; rt < 4; rt++)
            #pragma unroll
            for (int nt = 0; nt < 2; nt++)
                #pragma unroll
                for (int reg = 0; reg < 4; reg++)
                    aP[rt][nt * 4 + reg] = (__bf16)__builtin_amdgcn_exp2f(sv[nt][rt][reg]);
        __builtin_amdgcn_s_setprio(1);
        #pragma unroll
        for (int rt = 0; rt < 4; rt++) {
            #pragma unroll
            for (int dt = 0; dt < 4; dt++)
                outacc[rt][dt] = __builtin_amdgcn_mfma_f32_16x16x32_bf16(aP[rt], bV[dt], outacc[rt][dt], 0, 0, 0);
            accDen[rt] = __builtin_amdgcn_mfma_f32_16x16x32_bf16(aP[rt], bOne, accDen[rt], 0, 0, 0);
        }
        if (cc < 15) {
            #pragma unroll
            for (int nt = 0; nt < 2; nt++)
                #pragma unroll
                for (int rt = 0; rt < 4; rt++) {
                    f32x4 z = {0.f, 0.f, 0.f, 0.f};
                    z = __builtin_amdgcn_mfma_f32_16x16x32_bf16(bK2[nt][0], aQ4[rt][0], z, 0, 0, 0);
                    sv[nt][rt] = __builtin_amdgcn_mfma_f32_16x16x32_bf16(bK2[nt][1], aQ4[rt][1], z, 0, 0, 0);
                }
        }
        __builtin_amdgcn_s_setprio(0);
    }

    // ---- epilogue: rden directly from accDen (no cross-lane reduce) ------
    float rden[4][4];
    #pragma unroll
    for (int rt = 0; rt < 4; rt++)
        #pragma unroll
        for (int reg = 0; reg < 4; reg++)
            rden[rt][reg] = 1.0f / accDen[rt][reg];
    #pragma unroll
    for (int dt = 0; dt < 4; dt++) {
        float ps = 0.f;
        #pragma unroll
        for (int rt = 0; rt < 4; rt++)
            #pragma unroll
            for (int reg = 0; reg < 4; reg++)
                ps += outacc[rt][dt][reg] * rden[rt][reg];
        ps += __shfl_xor(ps, 16);
        ps += __shfl_xor(ps, 32);
        if (quad == 0) redw[dt * 16 + lc] = ps;   // xstage region (dead)
    }
    __syncthreads();
    if (t < 64) {
        float s = 0.f;
        #pragma unroll
        for (int ww = 0; ww < 8; ww++)
            s += *(const float*)(smem + 131072 + ww * 256 + t * 4);
        pooled[t] = s * (1.0f / 512.0f);
    }
    __syncthreads();
    if (t < NCLASS) {
        float acc = fcb[t];
        #pragma unroll
        for (int d = 0; d < 64; d++) acc += pooled[d] * fcw[t * 64 + d];
        outp[b * NCLASS + t] = acc;
    }
}

// ---------------------------------------------------------------------------
extern "C" void kernel_launch(void* const* d_in, const int* in_sizes, int n_in,
                              void* d_out, int out_size, void* d_ws, size_t ws_size,
                              hipStream_t stream)
{
    const float* x   = (const float*)d_in[0];
    const float* w1  = (const float*)d_in[1];
    const float* cb1 = (const float*)d_in[2];
    const float* g1  = (const float*)d_in[3];
    const float* be1 = (const float*)d_in[4];
    const float* m1  = (const float*)d_in[5];
    const float* v1  = (const float*)d_in[6];
    const float* w2  = (const float*)d_in[7];
    const float* cb2 = (const float*)d_in[8];
    const float* g2  = (const float*)d_in[9];
    const float* be2 = (const float*)d_in[10];
    const float* m2  = (const float*)d_in[11];
    const float* v2  = (const float*)d_in[12];
    const float* wq  = (const float*)d_in[13];
    const float* bq  = (const float*)d_in[14];
    const float* wk  = (const float*)d_in[15];
    const float* bk  = (const float*)d_in[16];
    const float* wv  = (const float*)d_in[17];
    const float* bv  = (const float*)d_in[18];
    const float* fcw = (const float*)d_in[19];
    const float* fcb = (const float*)d_in[20];
    float* out = (float*)d_out;
    (void)d_ws; (void)ws_size;

    fused_all<<<dim3(NB), 512, 0, stream>>>(x,
                                            w1, cb1, g1, be1, m1, v1,
                                            w2, cb2, g2, be2, m2, v2,
                                            wq, bq, wk, bk, wv, bv,
                                            fcw, fcb, out);
}

// Round 6
// 117.751 us; speedup vs baseline: 1.0566x; 1.0566x over previous
//
#include <hip/hip_runtime.h>
#include <hip/hip_bf16.h>

// B=256, C_IN=6, L=512, C1=32, C2=D=64, NCLASS=10.
// Megakernel v15 = v13 revert (two-kernel; v14's in-kernel weight fold
// regressed +4.5us: 256 concurrent blocks paying uncoalesced fold loads +
// raw-f32 weight gathers in front of the qkv MFMA chains) with ONE change:
// the softmax denominator moves OFF the MFMA pipe (the measured binding
// pipe, ~47% util) back to VALU accumulation: den[rt] += p inside the exp
// loop (64 VALU cy/chunk on a pipe with slack) replacing 4 ones-column
// MFMAs/chunk (78 cy/chunk on the binding pipe). Epilogue reduce restored
// (2 shfl_xor + 4 shfl per rt, one-time).
// LDS 139264 B (16 x 8192 slab + 8192 xstage). ws: prepped weights only.

#define NB 256
#define LL 512
#define CIN 6
#define NCLASS 10
#define SLAB 8192
#define QSC 0.18033688f   // 0.125 * log2(e): exp(s/8) == exp2(s*QSC)

typedef __bf16 bf16x8 __attribute__((ext_vector_type(8)));
typedef float f32x4 __attribute__((ext_vector_type(4)));
typedef unsigned short us4 __attribute__((ext_vector_type(4)));
typedef unsigned short us8 __attribute__((ext_vector_type(8)));
typedef unsigned int u32x4 __attribute__((ext_vector_type(4)));

static __device__ __forceinline__ unsigned short f2b(float f) {
    __bf16 h = (__bf16)f;                       // RNE f32->bf16
    return __builtin_bit_cast(unsigned short, h);
}

// ---------------------------------------------------------------------------
// Kernel P: 8-block weight fold (<1 us of compute).
// w1p[c][k'=dl*8+ci] = w1[c][ci*3+dl]*inv1 (zeros at ci>=6 or dl==3).
// w2p[c2][k'=dl*32+ci]*inv2; b1f/b2f folded.
// wqp/wkp/wvp laid out with sigma_h on the channel (contraction) dim:
//   slot k' (kc=k'>>5, quad=(k'>>3)&3, e=k'&7) <- ch = kc*32+(e>>2)*16+quad*4+(e&3)
// ---------------------------------------------------------------------------
__global__ __launch_bounds__(256) void prep_weights(
    const float* __restrict__ w1, const float* __restrict__ cb1,
    const float* __restrict__ g1, const float* __restrict__ be1,
    const float* __restrict__ m1, const float* __restrict__ v1,
    const float* __restrict__ w2, const float* __restrict__ cb2,
    const float* __restrict__ g2, const float* __restrict__ be2,
    const float* __restrict__ m2, const float* __restrict__ v2,
    const float* __restrict__ wq, const float* __restrict__ wk,
    const float* __restrict__ wv,
    unsigned short* __restrict__ w1p, float* __restrict__ b1f,
    unsigned short* __restrict__ w2p, float* __restrict__ b2f,
    unsigned short* __restrict__ wqp, unsigned short* __restrict__ wkp,
    unsigned short* __restrict__ wvp)
{
    const int tt = blockIdx.x * 256 + threadIdx.x;    // 0..2047
    for (int idx = tt; idx < 1024; idx += 2048) {     // w1p [32][32], k'=dl*8+ci
        int c = idx >> 5, k = idx & 31;
        int dl = k >> 3, ci = k & 7;
        float inv = g1[c] * rsqrtf(v1[c] + 1e-5f);
        float val = (dl < 3 && ci < 6) ? w1[c * 18 + ci * 3 + dl] * inv : 0.f;
        w1p[idx] = f2b(val);
    }
    if (tt < 32) {
        float inv = g1[tt] * rsqrtf(v1[tt] + 1e-5f);
        b1f[tt] = be1[tt] + (cb1[tt] - m1[tt]) * inv;
    }
    for (int idx = tt; idx < 2048; idx += 2048) {     // w2p [64][96], k'=dl*32+ci
        int c2 = idx >> 5, ci = idx & 31;
        float inv = g2[c2] * rsqrtf(v2[c2] + 1e-5f);
        const float* wp = w2 + c2 * 96 + ci * 3;
        w2p[c2 * 96 +      ci] = f2b(wp[0] * inv);
        w2p[c2 * 96 + 32 + ci] = f2b(wp[1] * inv);
        w2p[c2 * 96 + 64 + ci] = f2b(wp[2] * inv);
    }
    if (tt >= 64 && tt < 128) {
        int c2 = tt - 64;
        float inv = g2[c2] * rsqrtf(v2[c2] + 1e-5f);
        b2f[c2] = be2[c2] + (cb2[c2] - m2[c2]) * inv;
    }
    for (int idx = tt; idx < 4096; idx += 2048) {     // sigma_h permuted
        int d = idx >> 6, k = idx & 63;
        int kc = k >> 5, quad = (k >> 3) & 3, e = k & 7;
        int ch = kc * 32 + (e >> 2) * 16 + quad * 4 + (e & 3);
        wqp[idx] = f2b(wq[d * 64 + ch] * QSC);        // fold 1/8 * log2e
        wkp[idx] = f2b(wk[d * 64 + ch]);
        wvp[idx] = f2b(wv[d * 64 + ch]);
    }
}

// ---------------------------------------------------------------------------
// Megakernel v15. LDS: 16 slabs x 8192 B + xstage 8192 B = 139264 B.
// Slab g (g=2w+sg): conv: h1sl[34][40] @0 (dead before Kf written)
//                   attn: Kf @0 (4096) | Vf @4096 (4096, key-perm, frag order)
// xstage [512][8] u16 (dead after P1); epilogue redw/pooled in xstage region.
// ---------------------------------------------------------------------------
__global__ __launch_bounds__(512, 2) void fused_all(
    const float* __restrict__ x,
    const unsigned short* __restrict__ w1p, const float* __restrict__ b1f,
    const unsigned short* __restrict__ w2p, const float* __restrict__ b2f,
    const unsigned short* __restrict__ wqp, const unsigned short* __restrict__ wkp,
    const unsigned short* __restrict__ wvp,
    const float* __restrict__ bq, const float* __restrict__ bk,
    const float* __restrict__ bvp,
    const float* __restrict__ fcw, const float* __restrict__ fcb,
    float* __restrict__ outp)
{
    const int b = blockIdx.x;
    const int t = threadIdx.x;
    const int w = t >> 6, lane = t & 63, quad = lane >> 4, lc = lane & 15;

    __shared__ __align__(16) char smem[16 * SLAB + 8192];   // 139264 B
    unsigned short* xstage = (unsigned short*)(smem + 16 * SLAB);  // [512][8]
    float* redw   = (float*)(smem + 16 * SLAB) + w * 64;     // epilogue (xstage dead)
    float* pooled = (float*)(smem + 16 * SLAB + 4096);

    unsigned short* slab[2] = { (unsigned short*)(smem + (2 * w) * SLAB),
                                (unsigned short*)(smem + (2 * w + 1) * SLAB) };

    // ---- P0: stage x[b] transposed to [pos][ch(8)] bf16 (b128 rows) ------
    {
        us8 pk;
        #pragma unroll
        for (int ci = 0; ci < 6; ci++)
            pk[ci] = f2b(x[((size_t)b * CIN + ci) * LL + t]);  // coalesced per ci
        pk[6] = 0; pk[7] = 0;
        *(us8*)&xstage[t * 8] = pk;
    }
    __syncthreads();

    // ---- P1: conv1 swapped: h1 = mfma(W1, X), both groups ----------------
    {
        bf16x8 bW1[2];
        #pragma unroll
        for (int nt = 0; nt < 2; nt++)
            bW1[nt] = *(const bf16x8*)(w1p + (nt * 16 + lc) * 32 + quad * 8);
        f32x4 b1q[2];
        #pragma unroll
        for (int nt = 0; nt < 2; nt++)
            b1q[nt] = *(const f32x4*)&b1f[nt * 16 + quad * 4];
        #pragma unroll
        for (int sg = 0; sg < 2; sg++) {
            const int g = 2 * w + sg;
            unsigned short* h1sl = slab[sg];
            #pragma unroll
            for (int mt = 0; mt < 3; mt++) {
                int j = mt * 16 + lc;                 // 0..47, keep <34
                int P = g * 32 - 1 + j;               // output position (halo +-1)
                int src = P + quad - 1;               // x position for dl=quad
                bool okx = (src >= 0) && (src < LL);  // quad==3 -> weight is zero
                int srcc = src < 0 ? 0 : (src > 511 ? 511 : src);
                u32x4 xv = *(const u32x4*)&xstage[srcc * 8];
                if (!okx) { xv[0] = 0u; xv[1] = 0u; xv[2] = 0u; xv[3] = 0u; }
                bf16x8 aX = __builtin_bit_cast(bf16x8, xv);
                bool pv = (P >= 0) && (P < LL);
                #pragma unroll
                for (int nt = 0; nt < 2; nt++) {
                    f32x4 z = {0.f, 0.f, 0.f, 0.f};
                    f32x4 h = __builtin_amdgcn_mfma_f32_16x16x32_bf16(bW1[nt], aX, z, 0, 0, 0);
                    us4 pk;
                    #pragma unroll
                    for (int r = 0; r < 4; r++) {
                        float y = h[r] + b1q[nt][r];
                        y = (pv && y > 0.f) ? y : 0.f;
                        pk[r] = f2b(y);
                    }
                    if (j < 34)
                        *(us4*)&h1sl[j * 40 + nt * 16 + quad * 4] = pk;
                }
            }
        }
    }

    // ---- P2: conv2 as GEMM; weights loaded once, sg x rt chains ----------
    bf16x8 bX[2][2][3];                   // [sg][rt][kc]
    #pragma unroll
    for (int sg = 0; sg < 2; sg++)
        #pragma unroll
        for (int rt = 0; rt < 2; rt++)
            #pragma unroll
            for (int kc = 0; kc < 3; kc++)
                bX[sg][rt][kc] = *(const bf16x8*)&slab[sg][(rt * 16 + lc + kc) * 40 + quad * 8];

    f32x4 acc2[2][4][2];                  // [sg][nt][rt]
    #pragma unroll
    for (int nt = 0; nt < 4; nt++) {
        bf16x8 aW0 = *(const bf16x8*)(w2p + (nt * 16 + lc) * 96 + quad * 8);
        bf16x8 aW1 = *(const bf16x8*)(w2p + (nt * 16 + lc) * 96 + 32 + quad * 8);
        bf16x8 aW2 = *(const bf16x8*)(w2p + (nt * 16 + lc) * 96 + 64 + quad * 8);
        #pragma unroll
        for (int sg = 0; sg < 2; sg++)
            #pragma unroll
            for (int rt = 0; rt < 2; rt++) {
                f32x4 a = {0.f, 0.f, 0.f, 0.f};
                a = __builtin_amdgcn_mfma_f32_16x16x32_bf16(aW0, bX[sg][rt][0], a, 0, 0, 0);
                a = __builtin_amdgcn_mfma_f32_16x16x32_bf16(aW1, bX[sg][rt][1], a, 0, 0, 0);
                acc2[sg][nt][rt] = __builtin_amdgcn_mfma_f32_16x16x32_bf16(aW2, bX[sg][rt][2], a, 0, 0, 0);
            }
    }

    // ---- P3a: +b2f, relu -> aH in REGISTERS (sigma_h frag order) ---------
    bf16x8 aH[2][2][2];                   // [sg][rt][kc]
    #pragma unroll
    for (int nt2 = 0; nt2 < 4; nt2++) {
        f32x4 bb2 = *(const f32x4*)&b2f[nt2 * 16 + quad * 4];
        #pragma unroll
        for (int sg = 0; sg < 2; sg++)
            #pragma unroll
            for (int rt = 0; rt < 2; rt++)
                #pragma unroll
                for (int reg = 0; reg < 4; reg++) {
                    float y = acc2[sg][nt2][rt][reg] + bb2[reg];
                    aH[sg][rt][nt2 >> 1][(nt2 & 1) * 4 + reg] = (__bf16)(y > 0.f ? y : 0.f);
                }
    }

    // ---- biases for q/k (hoisted) ----------------------------------------
    f32x4 bbq[4], bbk[4];
    #pragma unroll
    for (int nt = 0; nt < 4; nt++) {
        bbq[nt] = *(const f32x4*)&bq[nt * 16 + quad * 4];
        bbk[nt] = *(const f32x4*)&bk[nt * 16 + quad * 4];
    }

    // ---- P3b-q: q fully in registers (sigma_d frag order), per-nt --------
    bf16x8 aQ4[4][2];                     // [rt4 = sg*2+rt][kc]
    #pragma unroll
    for (int nt = 0; nt < 4; nt++) {
        bf16x8 aW0 = *(const bf16x8*)(wqp + (nt * 16 + lc) * 64 + quad * 8);
        bf16x8 aW1 = *(const bf16x8*)(wqp + (nt * 16 + lc) * 64 + 32 + quad * 8);
        #pragma unroll
        for (int sg = 0; sg < 2; sg++)
            #pragma unroll
            for (int rt = 0; rt < 2; rt++) {
                f32x4 a = {0.f, 0.f, 0.f, 0.f};
                a = __builtin_amdgcn_mfma_f32_16x16x32_bf16(aW0, aH[sg][rt][0], a, 0, 0, 0);
                a = __builtin_amdgcn_mfma_f32_16x16x32_bf16(aW1, aH[sg][rt][1], a, 0, 0, 0);
                #pragma unroll
                for (int reg = 0; reg < 4; reg++)
                    aQ4[sg * 2 + rt][nt >> 1][(nt & 1) * 4 + reg] =
                        (__bf16)(a[reg] + bbq[nt][reg] * QSC);
            }
    }

    // ---- P3b-k: k -> Kf as 4 x b128 (sigma_d order), per-kc --------------
    #pragma unroll
    for (int kc = 0; kc < 2; kc++) {
        f32x4 Ck[2][2][2];                // [j][sg][rt], nt = kc*2+j
        #pragma unroll
        for (int j = 0; j < 2; j++) {
            int nt = kc * 2 + j;
            bf16x8 aW0 = *(const bf16x8*)(wkp + (nt * 16 + lc) * 64 + quad * 8);
            bf16x8 aW1 = *(const bf16x8*)(wkp + (nt * 16 + lc) * 64 + 32 + quad * 8);
            #pragma unroll
            for (int sg = 0; sg < 2; sg++)
                #pragma unroll
                for (int rt = 0; rt < 2; rt++) {
                    f32x4 a = {0.f, 0.f, 0.f, 0.f};
                    a = __builtin_amdgcn_mfma_f32_16x16x32_bf16(aW0, aH[sg][rt][0], a, 0, 0, 0);
                    Ck[j][sg][rt] = __builtin_amdgcn_mfma_f32_16x16x32_bf16(aW1, aH[sg][rt][1], a, 0, 0, 0);
                }
        }
        #pragma unroll
        for (int sg = 0; sg < 2; sg++)
            #pragma unroll
            for (int rt = 0; rt < 2; rt++) {
                us8 pk;
                #pragma unroll
                for (int e = 0; e < 8; e++) {
                    int j = e >> 2, reg = e & 3, nt = kc * 2 + j;
                    pk[e] = f2b(Ck[j][sg][rt][reg] + bbk[nt][reg]);
                }
                *(us8*)&slab[sg][((rt * 2 + kc) << 9) + lane * 8] = pk;   // Kf
            }
    }

    // ---- P3c: v -> Vf as 4 x b128 (key-permuted frag order), per-nt ------
    #pragma unroll
    for (int nt = 0; nt < 4; nt++) {
        bf16x8 bW0 = *(const bf16x8*)(wvp + (nt * 16 + lc) * 64 + quad * 8);
        bf16x8 bW1 = *(const bf16x8*)(wvp + (nt * 16 + lc) * 64 + 32 + quad * 8);
        const float bvv = bvp[nt * 16 + lc];
        #pragma unroll
        for (int sg = 0; sg < 2; sg++) {
            f32x4 a0, a1;
            {
                f32x4 z = {0.f, 0.f, 0.f, 0.f};
                z = __builtin_amdgcn_mfma_f32_16x16x32_bf16(aH[sg][0][0], bW0, z, 0, 0, 0);
                a0 = __builtin_amdgcn_mfma_f32_16x16x32_bf16(aH[sg][0][1], bW1, z, 0, 0, 0);
            }
            {
                f32x4 z = {0.f, 0.f, 0.f, 0.f};
                z = __builtin_amdgcn_mfma_f32_16x16x32_bf16(aH[sg][1][0], bW0, z, 0, 0, 0);
                a1 = __builtin_amdgcn_mfma_f32_16x16x32_bf16(aH[sg][1][1], bW1, z, 0, 0, 0);
            }
            us8 pk;
            #pragma unroll
            for (int reg = 0; reg < 4; reg++) {
                pk[reg]     = f2b(a0[reg] + bvv);
                pk[4 + reg] = f2b(a1[reg] + bvv);
            }
            *(us8*)&slab[sg][2048 + nt * 512 + lane * 8] = pk;            // Vf
        }
    }

    __syncthreads();          // all waves' Kf/Vf ready — only pre-attn barrier

    // ---- attention: 16 chunks, 64 q/wave, in-reg softmax, pipelined ------
    // sv[nt][rt4] holds QK(cc) computed at END of iter cc-1 (or prologue).
    // Denominator on the VALU pipe: den[rt] accumulates this lane's 8 keys'
    // exp for q=lc (full sum after the epilogue quad-reduce).
    f32x4 outacc[4][4];
    #pragma unroll
    for (int rt = 0; rt < 4; rt++)
        #pragma unroll
        for (int dt = 0; dt < 4; dt++) outacc[rt][dt] = (f32x4){0.f, 0.f, 0.f, 0.f};
    float den[4] = {0.f, 0.f, 0.f, 0.f};

    bf16x8 bK2[2][2];
    {
        const unsigned short* sK = (const unsigned short*)smem;   // chunk 0
        #pragma unroll
        for (int nt = 0; nt < 2; nt++)
            #pragma unroll
            for (int kc = 0; kc < 2; kc++)
                bK2[nt][kc] = *(const bf16x8*)&sK[((nt * 2 + kc) << 9) + lane * 8];
    }
    f32x4 sv[2][4];                               // [nt][rt4]
    #pragma unroll
    for (int nt = 0; nt < 2; nt++)
        #pragma unroll
        for (int rt = 0; rt < 4; rt++) {
            f32x4 z = {0.f, 0.f, 0.f, 0.f};
            z = __builtin_amdgcn_mfma_f32_16x16x32_bf16(bK2[nt][0], aQ4[rt][0], z, 0, 0, 0);
            sv[nt][rt] = __builtin_amdgcn_mfma_f32_16x16x32_bf16(bK2[nt][1], aQ4[rt][1], z, 0, 0, 0);
        }

    for (int cc = 0; cc < 16; cc++) {
        const unsigned short* sV = (const unsigned short*)(smem + cc * SLAB + 4096);
        bf16x8 bV[4];
        #pragma unroll
        for (int dt = 0; dt < 4; dt++)
            bV[dt] = *(const bf16x8*)&sV[dt * 512 + lane * 8];
        if (cc < 15) {                            // load next chunk's K frags
            const unsigned short* sKn = (const unsigned short*)(smem + (cc + 1) * SLAB);
            #pragma unroll
            for (int nt = 0; nt < 2; nt++)
                #pragma unroll
                for (int kc = 0; kc < 2; kc++)
                    bK2[nt][kc] = *(const bf16x8*)&sKn[((nt * 2 + kc) << 9) + lane * 8];
        }
        bf16x8 aP[4];
        #pragma unroll
        for (int rt = 0; rt < 4; rt++)
            #pragma unroll
            for (int nt = 0; nt < 2; nt++)
                #pragma unroll
                for (int reg = 0; reg < 4; reg++) {
                    float p = __builtin_amdgcn_exp2f(sv[nt][rt][reg]);
                    den[rt] += p;
                    aP[rt][nt * 4 + reg] = (__bf16)p;
                }
        __builtin_amdgcn_s_setprio(1);
        #pragma unroll
        for (int rt = 0; rt < 4; rt++)
            #pragma unroll
            for (int dt = 0; dt < 4; dt++)
                outacc[rt][dt] = __builtin_amdgcn_mfma_f32_16x16x32_bf16(aP[rt], bV[dt], outacc[rt][dt], 0, 0, 0);
        if (cc < 15) {
            #pragma unroll
            for (int nt = 0; nt < 2; nt++)
                #pragma unroll
                for (int rt = 0; rt < 4; rt++) {
                    f32x4 z = {0.f, 0.f, 0.f, 0.f};
                    z = __builtin_amdgcn_mfma_f32_16x16x32_bf16(bK2[nt][0], aQ4[rt][0], z, 0, 0, 0);
                    sv[nt][rt] = __builtin_amdgcn_mfma_f32_16x16x32_bf16(bK2[nt][1], aQ4[rt][1], z, 0, 0, 0);
                }
        }
        __builtin_amdgcn_s_setprio(0);
    }

    // ---- epilogue: den reduce (per q=lc, sum over quads), redistribute ---
    float rden[4][4];
    #pragma unroll
    for (int rt = 0; rt < 4; rt++) {
        float d2 = den[rt];
        d2 += __shfl_xor(d2, 16);
        d2 += __shfl_xor(d2, 32);
        d2 = 1.0f / d2;
        #pragma unroll
        for (int reg = 0; reg < 4; reg++)
            rden[rt][reg] = __shfl(d2, quad * 4 + reg);
    }
    #pragma unroll
    for (int dt = 0; dt < 4; dt++) {
        float ps = 0.f;
        #pragma unroll
        for (int rt = 0; rt < 4; rt++)
            #pragma unroll
            for (int reg = 0; reg < 4; reg++)
                ps += outacc[rt][dt][reg] * rden[rt][reg];
        ps += __shfl_xor(ps, 16);
        ps += __shfl_xor(ps, 32);
        if (quad == 0) redw[dt * 16 + lc] = ps;   // xstage region (dead)
    }
    __syncthreads();
    if (t < 64) {
        float s = 0.f;
        #pragma unroll
        for (int ww = 0; ww < 8; ww++)
            s += *(const float*)(smem + 16 * SLAB + ww * 256 + t * 4);
        pooled[t] = s * (1.0f / 512.0f);
    }
    __syncthreads();
    if (t < NCLASS) {
        float acc = fcb[t];
        #pragma unroll
        for (int d = 0; d < 64; d++) acc += pooled[d] * fcw[t * 64 + d];
        outp[b * NCLASS + t] = acc;
    }
}

// ---------------------------------------------------------------------------
extern "C" void kernel_launch(void* const* d_in, const int* in_sizes, int n_in,
                              void* d_out, int out_size, void* d_ws, size_t ws_size,
                              hipStream_t stream)
{
    const float* x   = (const float*)d_in[0];
    const float* w1  = (const float*)d_in[1];
    const float* cb1 = (const float*)d_in[2];
    const float* g1  = (const float*)d_in[3];
    const float* be1 = (const float*)d_in[4];
    const float* m1  = (const float*)d_in[5];
    const float* v1  = (const float*)d_in[6];
    const float* w2  = (const float*)d_in[7];
    const float* cb2 = (const float*)d_in[8];
    const float* g2  = (const float*)d_in[9];
    const float* be2 = (const float*)d_in[10];
    const float* m2  = (const float*)d_in[11];
    const float* v2  = (const float*)d_in[12];
    const float* wq  = (const float*)d_in[13];
    const float* bq  = (const float*)d_in[14];
    const float* wk  = (const float*)d_in[15];
    const float* bk  = (const float*)d_in[16];
    const float* wv  = (const float*)d_in[17];
    const float* bv  = (const float*)d_in[18];
    const float* fcw = (const float*)d_in[19];
    const float* fcb = (const float*)d_in[20];
    float* out = (float*)d_out;

    char* ws = (char*)d_ws;
    unsigned short* w1p = (unsigned short*)(ws);            // 2048 B
    float*          b1f = (float*)(ws + 2048u);             // 128 B
    float*          b2f = (float*)(ws + 2176u);             // 256 B
    unsigned short* w2p = (unsigned short*)(ws + 2432u);    // 12288 B
    unsigned short* wqp = (unsigned short*)(ws + 14720u);   // 8192 B
    unsigned short* wkp = (unsigned short*)(ws + 22912u);   // 8192 B
    unsigned short* wvp = (unsigned short*)(ws + 31104u);   // 8192 B

    prep_weights<<<dim3(8), 256, 0, stream>>>(w1, cb1, g1, be1, m1, v1,
                                              w2, cb2, g2, be2, m2, v2,
                                              wq, wk, wv,
                                              w1p, b1f, w2p, b2f, wqp, wkp, wvp);
    fused_all<<<dim3(NB), 512, 0, stream>>>(x, w1p, b1f, w2p, b2f,
                                            wqp, wkp, wvp,
                                            bq, bk, bv, fcw, fcb, out);
}